// Round 1
// baseline (684.988 us; speedup 1.0000x reference)
//
#include <hip/hip_runtime.h>
#include <hip/hip_bf16.h>

typedef __bf16 bf16_t;
typedef bf16_t bf16x8 __attribute__((ext_vector_type(8)));
typedef float f32x4 __attribute__((ext_vector_type(4)));

#define L_NUM 3
#define E_NUM 4
#define D_DIM 1024
#define R_DIM 64
#define B_ROWS 32768
#define BT 32
#define TPB 512
#define N1 272           // 256 V-cols + 4 gating cols + 12 zero pad
#define XL_STRIDE 1032   // 1024 + 8 pad (2064B row -> 2-way bank alias, free)
#define T1_STRIDE 264    // 256 + 8 pad (528B row -> 2-way bank alias, free)

#define VT_ELEMS (L_NUM * N1 * D_DIM)            // 835584
#define UT_ELEMS (L_NUM * D_DIM * 256)           // 786432
#define CB_ELEMS (L_NUM * E_NUM * R_DIM * R_DIM) // 49152

#define MFMA16(a, b, c) __builtin_amdgcn_mfma_f32_16x16x32_bf16((a), (b), (c), 0, 0, 0)

__device__ __forceinline__ ushort f2b(float f) {
  union { float f; unsigned u; } x; x.f = f;
  unsigned r = (x.u + 0x7fffu + ((x.u >> 16) & 1u)) >> 16;  // RNE
  return (ushort)r;
}
__device__ __forceinline__ float b2f(ushort h) {
  union { unsigned u; float f; } x; x.u = ((unsigned)h) << 16;
  return x.f;
}
__device__ __forceinline__ float tanh_fast(float x) {
  float cx = fminf(fmaxf(x, -15.f), 15.f);
  float e = __expf(2.f * cx);
  return (e - 1.f) / (e + 1.f);
}

// ---------------- weight prepack: f32 -> bf16, B^T ([N][K]) layouts ----------------

__global__ void pack_vt_kernel(const float* __restrict__ V, const float* __restrict__ gw,
                               ushort* __restrict__ vt) {
  int idx = blockIdx.x * 256 + threadIdx.x;
  if (idx >= VT_ELEMS) return;
  int d = idx & (D_DIM - 1);
  int n = (idx >> 10) % N1;
  int l = idx / (N1 * D_DIM);
  float val = 0.f;
  if (n < 256) {
    int e = n >> 6, r = n & 63;
    val = V[(((l * E_NUM + e) * D_DIM) + d) * R_DIM + r];   // Vt[l][e*64+r][d] = V[l,e,d,r]
  } else if (n < 260) {
    val = gw[(n - 256) * D_DIM + d];                        // gating cols
  }
  vt[idx] = f2b(val);
}

__global__ void pack_ut_kernel(const float* __restrict__ U, ushort* __restrict__ ut) {
  int idx = blockIdx.x * 256 + threadIdx.x;
  if (idx >= UT_ELEMS) return;
  int er = idx & 255;
  int d = (idx >> 8) & (D_DIM - 1);
  int l = idx >> 18;
  int e = er >> 6, r = er & 63;
  ut[idx] = f2b(U[((l * E_NUM + e) * D_DIM + d) * R_DIM + r]);  // Ut[l][d][e*64+r]
}

__global__ void pack_cb_kernel(const float* __restrict__ C, ushort* __restrict__ cb) {
  int idx = blockIdx.x * 256 + threadIdx.x;
  if (idx >= CB_ELEMS) return;
  cb[idx] = f2b(C[idx]);   // C[l,e,r,s] already is Bt[n=r][k=s]
}

// ---------------- fused 3-layer CrossNet: each block owns 32 rows end-to-end ----------------

__global__ __launch_bounds__(TPB, 2) void crossnet_fused(
    const float* __restrict__ inputs, const float* __restrict__ bias,
    const ushort* __restrict__ Vt, const ushort* __restrict__ Ut,
    const ushort* __restrict__ Cb, float* __restrict__ out) {
  __shared__ ushort xl[BT * XL_STRIDE];    // x_l bf16, A-operand for GEMM1 (66048 B)
  __shared__ ushort x0s[BT * XL_STRIDE];   // x0 bf16 (66048 B)
  __shared__ ushort t1[BT * T1_STRIDE];    // v1, later w = gate*v2 (16896 B)
  __shared__ float glog[BT * 4];
  __shared__ float gate[BT * 4];

  const int tid = threadIdx.x;
  const int wave = tid >> 6;
  const int lane = tid & 63;
  const int l15 = lane & 15;
  const int quad = lane >> 4;
  const long rowbase = (long)blockIdx.x * BT;

  // ---- stage inputs -> xl, x0s (coalesced float4) ----
  #pragma unroll
  for (int i = 0; i < 16; ++i) {
    int idx = tid + i * TPB;       // float4 index within [32][256]
    int r = idx >> 8;
    int c4 = idx & 255;
    float4 v = ((const float4*)(inputs + (rowbase + r) * D_DIM))[c4];
    ushort4 h;
    h.x = f2b(v.x); h.y = f2b(v.y); h.z = f2b(v.z); h.w = f2b(v.w);
    *(ushort4*)&xl[r * XL_STRIDE + c4 * 4] = h;
    *(ushort4*)&x0s[r * XL_STRIDE + c4 * 4] = h;
  }

  // ---- x_l kept in f32 registers at this wave's GEMM2 C-layout positions ----
  // wave owns cols [wave*128, wave*128+128); lane holds rows m*16+quad*4+rg, col nt*16+l15
  float xlr[8][2][4];
  #pragma unroll
  for (int nt = 0; nt < 8; ++nt)
    #pragma unroll
    for (int m = 0; m < 2; ++m)
      #pragma unroll
      for (int rg = 0; rg < 4; ++rg) {
        int row = m * 16 + quad * 4 + rg;
        int col = wave * 128 + nt * 16 + l15;
        xlr[nt][m][rg] = inputs[(rowbase + row) * D_DIM + col];
      }
  __syncthreads();

  const f32x4 zf = {0.f, 0.f, 0.f, 0.f};

  for (int l = 0; l < L_NUM; ++l) {
    const ushort* vtl = Vt + l * N1 * D_DIM;
    const ushort* utl = Ut + l * D_DIM * 256;
    const ushort* cbl = Cb + l * E_NUM * R_DIM * R_DIM;

    // ================= Phase A: GEMM1  T1[32,272] = xl[32,1024] @ [V|gw] =================
    f32x4 acc1[3][2];
    #pragma unroll
    for (int t = 0; t < 3; ++t) { acc1[t][0] = zf; acc1[t][1] = zf; }

    const ushort* xa0 = &xl[l15 * XL_STRIDE + quad * 8];
    const ushort* xa1 = &xl[(16 + l15) * XL_STRIDE + quad * 8];
    const ushort* vb0 = vtl + (wave * 32 + l15) * D_DIM + quad * 8;
    const ushort* vb1 = vb0 + 16 * D_DIM;
    if (wave == 7) {  // wave 7 also computes the gating tile (cols 256..271)
      const ushort* vb2 = vtl + (256 + l15) * D_DIM + quad * 8;
      #pragma unroll 4
      for (int k0 = 0; k0 < D_DIM; k0 += 32) {
        bf16x8 a0 = *(const bf16x8*)(xa0 + k0);
        bf16x8 a1 = *(const bf16x8*)(xa1 + k0);
        bf16x8 b0 = *(const bf16x8*)(vb0 + k0);
        bf16x8 b1 = *(const bf16x8*)(vb1 + k0);
        bf16x8 b2 = *(const bf16x8*)(vb2 + k0);
        acc1[0][0] = MFMA16(a0, b0, acc1[0][0]);
        acc1[0][1] = MFMA16(a1, b0, acc1[0][1]);
        acc1[1][0] = MFMA16(a0, b1, acc1[1][0]);
        acc1[1][1] = MFMA16(a1, b1, acc1[1][1]);
        acc1[2][0] = MFMA16(a0, b2, acc1[2][0]);
        acc1[2][1] = MFMA16(a1, b2, acc1[2][1]);
      }
    } else {
      #pragma unroll 4
      for (int k0 = 0; k0 < D_DIM; k0 += 32) {
        bf16x8 a0 = *(const bf16x8*)(xa0 + k0);
        bf16x8 a1 = *(const bf16x8*)(xa1 + k0);
        bf16x8 b0 = *(const bf16x8*)(vb0 + k0);
        bf16x8 b1 = *(const bf16x8*)(vb1 + k0);
        acc1[0][0] = MFMA16(a0, b0, acc1[0][0]);
        acc1[0][1] = MFMA16(a1, b0, acc1[0][1]);
        acc1[1][0] = MFMA16(a0, b1, acc1[1][0]);
        acc1[1][1] = MFMA16(a1, b1, acc1[1][1]);
      }
    }

    // epilogue: v1 = tanh(T1) -> t1 (bf16); gating logits -> glog (f32)
    #pragma unroll
    for (int t = 0; t < 2; ++t) {
      int ncol = wave * 32 + t * 16 + l15;
      #pragma unroll
      for (int m = 0; m < 2; ++m)
        #pragma unroll
        for (int rg = 0; rg < 4; ++rg) {
          int row = m * 16 + quad * 4 + rg;
          t1[row * T1_STRIDE + ncol] = f2b(tanh_fast(acc1[t][m][rg]));
        }
    }
    if (wave == 7 && l15 < 4) {
      #pragma unroll
      for (int m = 0; m < 2; ++m)
        #pragma unroll
        for (int rg = 0; rg < 4; ++rg)
          glog[(m * 16 + quad * 4 + rg) * 4 + l15] = acc1[2][m][rg];
    }
    __syncthreads();

    // ================= Phase B: softmax over E=4 (threads 0..31, one row each) =================
    if (tid < BT) {
      float g0 = glog[tid * 4 + 0], g1 = glog[tid * 4 + 1];
      float g2 = glog[tid * 4 + 2], g3 = glog[tid * 4 + 3];
      float mx = fmaxf(fmaxf(g0, g1), fmaxf(g2, g3));
      float e0 = __expf(g0 - mx), e1 = __expf(g1 - mx);
      float e2 = __expf(g2 - mx), e3 = __expf(g3 - mx);
      float inv = 1.f / (e0 + e1 + e2 + e3);
      gate[tid * 4 + 0] = e0 * inv; gate[tid * 4 + 1] = e1 * inv;
      gate[tid * 4 + 2] = e2 * inv; gate[tid * 4 + 3] = e3 * inv;
    }

    // ================= Phase C: block-diag v2 = tanh(C @ v1), w = gate*v2 =================
    const int e = wave >> 1;   // expert
    const int nh = wave & 1;   // which 32-col half of the 64 r-outputs
    f32x4 acc2[2][2];
    acc2[0][0] = zf; acc2[0][1] = zf; acc2[1][0] = zf; acc2[1][1] = zf;
    #pragma unroll
    for (int k0 = 0; k0 < 64; k0 += 32) {
      bf16x8 a0 = *(const bf16x8*)&t1[l15 * T1_STRIDE + e * 64 + k0 + quad * 8];
      bf16x8 a1 = *(const bf16x8*)&t1[(16 + l15) * T1_STRIDE + e * 64 + k0 + quad * 8];
      bf16x8 b0 = *(const bf16x8*)&cbl[(e * 64 + nh * 32 + l15) * 64 + k0 + quad * 8];
      bf16x8 b1 = *(const bf16x8*)&cbl[(e * 64 + nh * 32 + 16 + l15) * 64 + k0 + quad * 8];
      acc2[0][0] = MFMA16(a0, b0, acc2[0][0]);
      acc2[0][1] = MFMA16(a1, b0, acc2[0][1]);
      acc2[1][0] = MFMA16(a0, b1, acc2[1][0]);
      acc2[1][1] = MFMA16(a1, b1, acc2[1][1]);
    }
    __syncthreads();  // all v1 reads done; gate ready -> safe to overwrite t1 with w
    #pragma unroll
    for (int t = 0; t < 2; ++t) {
      int ncol = e * 64 + nh * 32 + t * 16 + l15;
      #pragma unroll
      for (int m = 0; m < 2; ++m)
        #pragma unroll
        for (int rg = 0; rg < 4; ++rg) {
          int row = m * 16 + quad * 4 + rg;
          float g = gate[row * 4 + e];
          t1[row * T1_STRIDE + ncol] = f2b(g * tanh_fast(acc2[t][m][rg]));
        }
    }
    __syncthreads();

    // ================= Phase D: GEMM2  S[32,1024] = w[32,256] @ Ut^T =================
    f32x4 acc3[8][2];
    #pragma unroll
    for (int nt = 0; nt < 8; ++nt) { acc3[nt][0] = zf; acc3[nt][1] = zf; }
    const ushort* wa0 = &t1[l15 * T1_STRIDE + quad * 8];
    const ushort* wa1 = &t1[(16 + l15) * T1_STRIDE + quad * 8];
    const ushort* ub = utl + (wave * 128 + l15) * 256 + quad * 8;
    #pragma unroll 2
    for (int k0 = 0; k0 < 256; k0 += 32) {
      bf16x8 a0 = *(const bf16x8*)(wa0 + k0);
      bf16x8 a1 = *(const bf16x8*)(wa1 + k0);
      #pragma unroll
      for (int nt = 0; nt < 8; ++nt) {
        bf16x8 b = *(const bf16x8*)(ub + nt * 16 * 256 + k0);
        acc3[nt][0] = MFMA16(a0, b, acc3[nt][0]);
        acc3[nt][1] = MFMA16(a1, b, acc3[nt][1]);
      }
    }

    // epilogue: x_new = x_l + x0*(S + bias[l]); update f32 regs + bf16 LDS shadow
    #pragma unroll
    for (int nt = 0; nt < 8; ++nt) {
      int col = wave * 128 + nt * 16 + l15;
      float bv = bias[l * D_DIM + col];
      #pragma unroll
      for (int m = 0; m < 2; ++m)
        #pragma unroll
        for (int rg = 0; rg < 4; ++rg) {
          int row = m * 16 + quad * 4 + rg;
          float x0v = b2f(x0s[row * XL_STRIDE + col]);
          float xn = xlr[nt][m][rg] + x0v * (acc3[nt][m][rg] + bv);
          xlr[nt][m][rg] = xn;
          xl[row * XL_STRIDE + col] = f2b(xn);
        }
    }
    __syncthreads();  // xl/t1 safe for next layer
  }

  // ---- final store (f32 residual path, full precision) ----
  #pragma unroll
  for (int nt = 0; nt < 8; ++nt) {
    int col = wave * 128 + nt * 16 + l15;
    #pragma unroll
    for (int m = 0; m < 2; ++m)
      #pragma unroll
      for (int rg = 0; rg < 4; ++rg) {
        int row = m * 16 + quad * 4 + rg;
        out[(rowbase + row) * D_DIM + col] = xlr[nt][m][rg];
      }
  }
}

extern "C" void kernel_launch(void* const* d_in, const int* in_sizes, int n_in,
                              void* d_out, int out_size, void* d_ws, size_t ws_size,
                              hipStream_t stream) {
  (void)in_sizes; (void)n_in; (void)out_size; (void)ws_size;
  const float* inputs = (const float*)d_in[0];
  const float* U      = (const float*)d_in[1];
  const float* V      = (const float*)d_in[2];
  const float* C      = (const float*)d_in[3];
  const float* gw     = (const float*)d_in[4];
  const float* bias   = (const float*)d_in[5];
  float* out = (float*)d_out;

  ushort* vt = (ushort*)d_ws;          // 3*272*1024 bf16
  ushort* ut = vt + VT_ELEMS;          // 3*1024*256 bf16
  ushort* cb = ut + UT_ELEMS;          // 3*4*64*64  bf16

  pack_vt_kernel<<<(VT_ELEMS + 255) / 256, 256, 0, stream>>>(V, gw, vt);
  pack_ut_kernel<<<(UT_ELEMS + 255) / 256, 256, 0, stream>>>(U, ut);
  pack_cb_kernel<<<(CB_ELEMS + 255) / 256, 256, 0, stream>>>(C, cb);

  crossnet_fused<<<B_ROWS / BT, TPB, 0, stream>>>(inputs, bias, vt, ut, cb, out);
}